// Round 1
// baseline (273.047 us; speedup 1.0000x reference)
//
#include <hip/hip_runtime.h>

typedef __attribute__((ext_vector_type(8))) short short8;
typedef __attribute__((ext_vector_type(4))) float floatx4;

#define HW 4096
#define CIN 256
#define CK 128
#define COUT 256
#define NB 4
#define BN_EPS 1e-5f
#define SCALE 0.08838834764831843f

#define MFMA(a, b, c) __builtin_amdgcn_mfma_f32_16x16x32_bf16((a), (b), (c), 0, 0, 0)

__device__ __forceinline__ unsigned short f2bf(float f) {
  union { float f; unsigned u; } v; v.f = f;
  unsigned r = v.u + 0x7fffu + ((v.u >> 16) & 1u);  // RNE
  return (unsigned short)(r >> 16);
}

__device__ __forceinline__ short8 pack8(const float* p) {
  short8 r;
#pragma unroll
  for (int i = 0; i < 8; ++i) r[i] = (short)f2bf(p[i]);
  return r;
}

// ---------------------------------------------------------------------------
// Kernel 1: QKV projections + BN/ReLU epilogue.
// grid (64 p-tiles, 4 batch, 3 proj), block 256.
// Q -> Qb[b][p][c] bf16 ; K -> Kb[b][p][c] bf16 ; V -> Vt[b][c][p] bf16.
// ---------------------------------------------------------------------------
__global__ __launch_bounds__(256) void proj_kernel(
    const float* __restrict__ x_enc, const float* __restrict__ x_dec,
    const float* __restrict__ wq, const float* __restrict__ bq,
    const float* __restrict__ gq, const float* __restrict__ betaq,
    const float* __restrict__ mq, const float* __restrict__ vq,
    const float* __restrict__ wk, const float* __restrict__ bk,
    const float* __restrict__ gk, const float* __restrict__ betak,
    const float* __restrict__ mk, const float* __restrict__ vk,
    const float* __restrict__ wv, const float* __restrict__ bv,
    unsigned short* __restrict__ Qb, unsigned short* __restrict__ Kb,
    unsigned short* __restrict__ Vt)
{
  const int tid = threadIdx.x;
  const int pt = blockIdx.x;  // p-tile (64 positions)
  const int b  = blockIdx.y;
  const int pj = blockIdx.z;  // 0:Q(x_dec) 1:K(x_enc) 2:V(x_enc)

  const float* X = (pj == 0) ? x_dec : x_enc;
  const float* W = (pj == 0) ? wq : (pj == 1 ? wk : wv);

  __shared__ unsigned short xT[64 * 264];  // [p][c], stride 264 (16B-aligned rows)

  // Stage + transpose x tile [256 c][64 p] -> xT[p][c] (bf16)
  {
    const float* Xs = X + (size_t)b * CIN * HW + (size_t)pt * 64;
    const int tr = tid >> 4;   // 0..15 (c row within pass)
    const int tc = tid & 15;   // 0..15 (4-float chunk along p)
#pragma unroll
    for (int pass = 0; pass < 16; ++pass) {
      const int c = pass * 16 + tr;
      const float4 v = *(const float4*)(Xs + (size_t)c * HW + tc * 4);
      xT[(tc * 4 + 0) * 264 + c] = f2bf(v.x);
      xT[(tc * 4 + 1) * 264 + c] = f2bf(v.y);
      xT[(tc * 4 + 2) * 264 + c] = f2bf(v.z);
      xT[(tc * 4 + 3) * 264 + c] = f2bf(v.w);
    }
  }
  __syncthreads();

  const int wave = tid >> 6;
  const int lane = tid & 63;
  const int lane16 = lane & 15;
  const int quad = lane >> 4;

  floatx4 acc[2][4];
#pragma unroll
  for (int mt = 0; mt < 2; ++mt)
#pragma unroll
    for (int nf = 0; nf < 4; ++nf) acc[mt][nf] = (floatx4){0.f, 0.f, 0.f, 0.f};

  // out^T = W @ x : M = o (this wave: 32 rows), N = p (64), K = c (256)
#pragma unroll
  for (int ks = 0; ks < 8; ++ks) {
    short8 af[2];
#pragma unroll
    for (int mt = 0; mt < 2; ++mt) {
      const int o = wave * 32 + mt * 16 + lane16;
      const float* Wr = W + (size_t)o * CIN + ks * 32 + quad * 8;
      float t[8];
      *(float4*)(t) = *(const float4*)(Wr);
      *(float4*)(t + 4) = *(const float4*)(Wr + 4);
      af[mt] = pack8(t);
    }
#pragma unroll
    for (int nf = 0; nf < 4; ++nf) {
      const short8 bf = *(const short8*)&xT[(nf * 16 + lane16) * 264 + ks * 32 + quad * 8];
#pragma unroll
      for (int mt = 0; mt < 2; ++mt) acc[mt][nf] = MFMA(af[mt], bf, acc[mt][nf]);
    }
  }

  if (pj == 2) {
    // V: bias only, store transposed Vt[b][c][p]
#pragma unroll
    for (int mt = 0; mt < 2; ++mt) {
#pragma unroll
      for (int r = 0; r < 4; ++r) {
        const int c = wave * 32 + mt * 16 + quad * 4 + r;
        const float bias = bv[c];
        unsigned short* dst = Vt + ((size_t)(b * CK + c)) * HW + pt * 64;
#pragma unroll
        for (int nf = 0; nf < 4; ++nf)
          dst[nf * 16 + lane16] = f2bf(acc[mt][nf][r] + bias);
      }
    }
  } else {
    const float* bias  = pj ? bk : bq;
    const float* gamma = pj ? gk : gq;
    const float* beta  = pj ? betak : betaq;
    const float* mean  = pj ? mk : mq;
    const float* var   = pj ? vk : vq;
    unsigned short* Out = pj ? Kb : Qb;
    float sc[2][4], off[2][4];
#pragma unroll
    for (int mt = 0; mt < 2; ++mt)
#pragma unroll
      for (int r = 0; r < 4; ++r) {
        const int o = wave * 32 + mt * 16 + quad * 4 + r;
        const float s = gamma[o] * rsqrtf(var[o] + BN_EPS);
        sc[mt][r] = s;
        off[mt][r] = (bias[o] - mean[o]) * s + beta[o];
      }
#pragma unroll
    for (int nf = 0; nf < 4; ++nf) {
      const size_t prow = ((size_t)b * HW + pt * 64 + nf * 16 + lane16) * CK;
#pragma unroll
      for (int mt = 0; mt < 2; ++mt) {
        ushort4 pk;
        pk.x = f2bf(fmaxf(acc[mt][nf][0] * sc[mt][0] + off[mt][0], 0.f));
        pk.y = f2bf(fmaxf(acc[mt][nf][1] * sc[mt][1] + off[mt][1], 0.f));
        pk.z = f2bf(fmaxf(acc[mt][nf][2] * sc[mt][2] + off[mt][2], 0.f));
        pk.w = f2bf(fmaxf(acc[mt][nf][3] * sc[mt][3] + off[mt][3], 0.f));
        *(ushort4*)(Out + prow + wave * 32 + mt * 16 + quad * 4) = pk;
      }
    }
  }
}

// ---------------------------------------------------------------------------
// Kernel 2: flash attention. grid 256 (b = blk&3, qtile = blk>>2), block 256.
// Each wave owns 16 q rows; 64 key-tiles of 64. ctx[b][q][c] bf16 out.
// ---------------------------------------------------------------------------
__global__ __launch_bounds__(256) void attn_kernel(
    const unsigned short* __restrict__ Qb, const unsigned short* __restrict__ Kb,
    const unsigned short* __restrict__ Vt, unsigned short* __restrict__ ctx)
{
  const int tid = threadIdx.x;
  const int b = blockIdx.x & 3;        // batch -> XCD-spread for K/V L2 reuse
  const int qt = blockIdx.x >> 2;      // 0..63
  const int wave = tid >> 6;
  const int lane = tid & 63;
  const int lane16 = lane & 15;
  const int quad = lane >> 4;

  __shared__ unsigned short Kl[64 * 136];    // [kp][c] stride 136
  __shared__ unsigned short Vl[128 * 72];    // [c][kp] stride 72
  __shared__ unsigned short Pl[4][16 * 72];  // per-wave [q][kp] stride 72

  // Persistent Q A-fragments (A: m=lane16, k=quad*8+j)
  short8 qf[4];
  {
    const unsigned short* Qs = Qb + ((size_t)b * HW + qt * 64 + wave * 16 + lane16) * CK;
#pragma unroll
    for (int ks = 0; ks < 4; ++ks) qf[ks] = *(const short8*)(Qs + ks * 32 + quad * 8);
  }

  float m_r[4], l_r[4];
  floatx4 O[8];
#pragma unroll
  for (int r = 0; r < 4; ++r) { m_r[r] = -1e30f; l_r[r] = 0.f; }
#pragma unroll
  for (int nf = 0; nf < 8; ++nf) O[nf] = (floatx4){0.f, 0.f, 0.f, 0.f};

  const unsigned short* Ksrc0 = Kb + (size_t)b * HW * CK;
  const unsigned short* Vsrc0 = Vt + (size_t)b * CK * HW;

  for (int kt = 0; kt < 64; ++kt) {
    __syncthreads();
    // stage K tile [64 kp][128 c] and V tile [128 c][64 kp]
    {
      const unsigned short* Ks = Ksrc0 + (size_t)(kt * 64) * CK;
      const int r = tid >> 4, cc = tid & 15;
#pragma unroll
      for (int pass = 0; pass < 4; ++pass) {
        const int row = pass * 16 + r;
        *(short8*)&Kl[row * 136 + cc * 8] = *(const short8*)(Ks + row * CK + cc * 8);
      }
      const unsigned short* Vs = Vsrc0 + kt * 64;
      const int vr = tid >> 3, vc = tid & 7;
#pragma unroll
      for (int pass = 0; pass < 4; ++pass) {
        const int row = pass * 32 + vr;
        *(short8*)&Vl[row * 72 + vc * 8] = *(const short8*)(Vs + (size_t)row * HW + vc * 8);
      }
    }
    __syncthreads();

    // S = Q K^T  (16 q x 64 kp)
    floatx4 S[4];
#pragma unroll
    for (int nf = 0; nf < 4; ++nf) S[nf] = (floatx4){0.f, 0.f, 0.f, 0.f};
#pragma unroll
    for (int ks = 0; ks < 4; ++ks) {
#pragma unroll
      for (int nf = 0; nf < 4; ++nf) {
        const short8 kf = *(const short8*)&Kl[(nf * 16 + lane16) * 136 + ks * 32 + quad * 8];
        S[nf] = MFMA(qf[ks], kf, S[nf]);
      }
    }

    // online softmax (rows live in 16-lane groups of each quad)
    float mnew[4], alpha[4];
#pragma unroll
    for (int r = 0; r < 4; ++r) {
      float t = fmaxf(fmaxf(S[0][r], S[1][r]), fmaxf(S[2][r], S[3][r])) * SCALE;
      t = fmaxf(t, __shfl_xor(t, 1));
      t = fmaxf(t, __shfl_xor(t, 2));
      t = fmaxf(t, __shfl_xor(t, 4));
      t = fmaxf(t, __shfl_xor(t, 8));
      mnew[r] = fmaxf(m_r[r], t);
      alpha[r] = __expf(m_r[r] - mnew[r]);
      m_r[r] = mnew[r];
    }
    float P[4][4];
#pragma unroll
    for (int nf = 0; nf < 4; ++nf)
#pragma unroll
      for (int r = 0; r < 4; ++r) P[nf][r] = __expf(S[nf][r] * SCALE - mnew[r]);
#pragma unroll
    for (int r = 0; r < 4; ++r) {
      float s = (P[0][r] + P[1][r]) + (P[2][r] + P[3][r]);
      s += __shfl_xor(s, 1);
      s += __shfl_xor(s, 2);
      s += __shfl_xor(s, 4);
      s += __shfl_xor(s, 8);
      l_r[r] = l_r[r] * alpha[r] + s;
    }

    // P: D-layout -> LDS -> A-layout (per-wave private region)
    unsigned short* Pw = &Pl[wave][0];
#pragma unroll
    for (int nf = 0; nf < 4; ++nf)
#pragma unroll
      for (int r = 0; r < 4; ++r)
        Pw[(quad * 4 + r) * 72 + nf * 16 + lane16] = f2bf(P[nf][r]);

#pragma unroll
    for (int nf = 0; nf < 8; ++nf)
#pragma unroll
      for (int r = 0; r < 4; ++r) O[nf][r] *= alpha[r];

    __threadfence_block();  // order P ds_write before cross-lane ds_read

    // O += P V  (16 q x 128 c)
#pragma unroll
    for (int ks = 0; ks < 2; ++ks) {
      const short8 pf = *(const short8*)&Pw[lane16 * 72 + ks * 32 + quad * 8];
#pragma unroll
      for (int nf = 0; nf < 8; ++nf) {
        const short8 vf = *(const short8*)&Vl[(nf * 16 + lane16) * 72 + ks * 32 + quad * 8];
        O[nf] = MFMA(pf, vf, O[nf]);
      }
    }
  }

  float inv[4];
#pragma unroll
  for (int r = 0; r < 4; ++r) inv[r] = 1.f / l_r[r];
  unsigned short* Cs = ctx + ((size_t)b * HW + qt * 64 + wave * 16) * CK;
#pragma unroll
  for (int nf = 0; nf < 8; ++nf)
#pragma unroll
    for (int r = 0; r < 4; ++r)
      Cs[(size_t)(quad * 4 + r) * CK + nf * 16 + lane16] = f2bf(O[nf][r] * inv[r]);
}

// ---------------------------------------------------------------------------
// Kernel 3: out = Wo @ ctx^T + bo. grid (64 p-tiles, 4 batch), block 256.
// ---------------------------------------------------------------------------
__global__ __launch_bounds__(256) void outproj_kernel(
    const unsigned short* __restrict__ ctx, const float* __restrict__ wo,
    const float* __restrict__ bo, float* __restrict__ out)
{
  const int tid = threadIdx.x;
  const int pt = blockIdx.x;
  const int b  = blockIdx.y;
  const int wave = tid >> 6;
  const int lane = tid & 63;
  const int lane16 = lane & 15;
  const int quad = lane >> 4;

  floatx4 acc[4][4];
#pragma unroll
  for (int mt = 0; mt < 4; ++mt)
#pragma unroll
    for (int nf = 0; nf < 4; ++nf) acc[mt][nf] = (floatx4){0.f, 0.f, 0.f, 0.f};

#pragma unroll
  for (int ks = 0; ks < 4; ++ks) {
    short8 af[4];
#pragma unroll
    for (int mt = 0; mt < 4; ++mt) {
      const int o = wave * 64 + mt * 16 + lane16;
      const float* Wr = wo + (size_t)o * CK + ks * 32 + quad * 8;
      float t[8];
      *(float4*)(t) = *(const float4*)(Wr);
      *(float4*)(t + 4) = *(const float4*)(Wr + 4);
      af[mt] = pack8(t);
    }
#pragma unroll
    for (int nf = 0; nf < 4; ++nf) {
      const short8 bf = *(const short8*)(ctx + ((size_t)b * HW + pt * 64 + nf * 16 + lane16) * CK + ks * 32 + quad * 8);
#pragma unroll
      for (int mt = 0; mt < 4; ++mt) acc[mt][nf] = MFMA(af[mt], bf, acc[mt][nf]);
    }
  }

#pragma unroll
  for (int mt = 0; mt < 4; ++mt) {
#pragma unroll
    for (int r = 0; r < 4; ++r) {
      const int o = wave * 64 + mt * 16 + quad * 4 + r;
      const float bias = bo[o];
      float* dst = out + ((size_t)b * COUT + o) * HW + pt * 64;
#pragma unroll
      for (int nf = 0; nf < 4; ++nf)
        dst[nf * 16 + lane16] = acc[mt][nf][r] + bias;
    }
  }
}

extern "C" void kernel_launch(void* const* d_in, const int* in_sizes, int n_in,
                              void* d_out, int out_size, void* d_ws, size_t ws_size,
                              hipStream_t stream)
{
  (void)in_sizes; (void)n_in; (void)out_size; (void)ws_size;
  const float* x_enc = (const float*)d_in[0];
  const float* x_dec = (const float*)d_in[1];
  const float* wk    = (const float*)d_in[2];
  const float* bk    = (const float*)d_in[3];
  const float* gk    = (const float*)d_in[4];
  const float* betak = (const float*)d_in[5];
  const float* mk    = (const float*)d_in[6];
  const float* vk    = (const float*)d_in[7];
  const float* wq    = (const float*)d_in[8];
  const float* bq    = (const float*)d_in[9];
  const float* gq    = (const float*)d_in[10];
  const float* betaq = (const float*)d_in[11];
  const float* mq    = (const float*)d_in[12];
  const float* vq    = (const float*)d_in[13];
  const float* wv    = (const float*)d_in[14];
  const float* bv    = (const float*)d_in[15];
  const float* wo    = (const float*)d_in[16];
  const float* bo    = (const float*)d_in[17];
  float* out = (float*)d_out;

  unsigned short* Qb  = (unsigned short*)d_ws;
  unsigned short* Kb  = Qb + (size_t)NB * HW * CK;
  unsigned short* Vt  = Kb + (size_t)NB * HW * CK;
  unsigned short* ctx = Vt + (size_t)NB * HW * CK;

  proj_kernel<<<dim3(64, 4, 3), 256, 0, stream>>>(
      x_enc, x_dec, wq, bq, gq, betaq, mq, vq,
      wk, bk, gk, betak, mk, vk, wv, bv, Qb, Kb, Vt);
  attn_kernel<<<dim3(256), 256, 0, stream>>>(Qb, Kb, Vt, ctx);
  outproj_kernel<<<dim3(64, 4), 256, 0, stream>>>(ctx, wo, bo, out);
}